// Round 7
// baseline (149.370 us; speedup 1.0000x reference)
//
#include <hip/hip_runtime.h>
#include <math.h>
#include <limits.h>

#define kB 4
#define kC 8
#define kH 384
#define kW 384
#define kCH (kC * kH)   // 3072
#define kIN (2 * kCH)   // 6144
#define kNC 18
#define kMID (kW / 2)

#define NCH 8                 // row chunks
#define RPC (kCH / NCH)       // 384 rows per chunk
#define NGRP 48               // column groups of 8
#define kN (kB * kW * kNC)    // 27648 floats per dense P array

#define E18(M) M(0) M(1) M(2) M(3) M(4) M(5) M(6) M(7) M(8) M(9) M(10) M(11) M(12) M(13) M(14) M(15) M(16) M(17)
#define E12(M) M(0) M(1) M(2) M(3) M(4) M(5) M(6) M(7) M(8) M(9) M(10) M(11)

// Wave-0 in-register computation of faithful left/right from acquired_mask
// (argmax(<1) semantics, 0 if none). Result in sLR[0]=candL, sLR[1]=candR.
__device__ __forceinline__ void mask_wave0(const float* __restrict__ am, int b,
                                           int lane, int wave, int* sLR) {
    if (wave == 0) {
        int candR = INT_MAX, candL = INT_MAX;
#pragma unroll
        for (int k = 0; k < 3; ++k) {
            int i = lane + 64 * k;
            if (am[b * kW + kMID + i] < 1.0f) candR = min(candR, i);
            if (am[b * kW + (kMID - 1 - i)] < 1.0f) candL = min(candL, i);
        }
#pragma unroll
        for (int off = 32; off; off >>= 1) {
            candR = min(candR, __shfl_down(candR, off, 64));
            candL = min(candL, __shfl_down(candL, off, 64));
        }
        if (lane == 0) { sLR[0] = candL; sLR[1] = candR; }
    }
}

// --------------------------------------------------------------------------
// K1: grid (48 col-groups, 8 row-chunks, B). 256 threads = 8 cols x 32 rows.
// Wave-0 register mask (2 barriers/block total instead of 9). Per pass: hoist
// all 12 coalesced k-space float2 loads, stage the 384-row W1 chunk to LDS,
// LDS-vector FMA, cross-lane reduce, write [8 cols][18] partial.
// --------------------------------------------------------------------------
__global__ __launch_bounds__(256)
void proj_kernel(const float* __restrict__ acquired,
                 const float* __restrict__ acquiring,
                 const float* __restrict__ am,
                 const float* __restrict__ qm,
                 const float* __restrict__ W1,
                 float* __restrict__ Pq_part, float* __restrict__ Pa_part) {
    int g = blockIdx.x, chunk = blockIdx.y, b = blockIdx.z;
    int tid = threadIdx.x;
    int w0 = g * 8, r0 = chunk * RPC;
    int lane = tid & 63, wave = tid >> 6;

    __shared__ int sLR[2];
    __shared__ float sQm[8];
    mask_wave0(am, b, lane, wave, sLR);
    if (wave == 1 && lane < 8) sQm[lane] = qm[b * kW + w0 + lane];
    __syncthreads();
    int left  = ((sLR[0] == INT_MAX) ? 0 : sLR[0]) + 1;
    int right = kMID + ((sLR[1] == INT_MAX) ? 0 : sLR[1]);

    bool band = (left < w0 + 8) && (right > w0);
    bool acq_any = (sQm[0] > 0.f) || (sQm[1] > 0.f) || (sQm[2] > 0.f) || (sQm[3] > 0.f) ||
                   (sQm[4] > 0.f) || (sQm[5] > 0.f) || (sQm[6] > 0.f) || (sQm[7] > 0.f);
    if (!band && !acq_any) return;

    int c8 = tid & 7, r32 = tid >> 3;
    int w = w0 + c8;

    __shared__ float sW[RPC][20];        // 30720 B; 80B rows keep 16B alignment
    __shared__ float sRed[4][8][kNC];

    for (int pass = 0; pass < 2; ++pass) {
        bool need = (pass == 0) ? band : acq_any;
        if (!need) continue;
        const float* ks = (pass == 0) ? acquired : acquiring;
        const float* w1 = (pass == 0) ? (W1 + kCH) : W1;  // acquired->W1[:,CH:], acquiring->W1[:,:CH]

        // ---- hoist all k-space loads (rows r32 + 32*it), coalesced 64B/row
        const float* colp = ks + ((size_t)(b * kCH + r0 + r32) * kW + w) * 2;
#define KLOAD(it) const float2 v##it = *reinterpret_cast<const float2*>(colp + (size_t)(it) * 32 * kW * 2);
        E12(KLOAD)
#define KMAG(it) const float f##it = sqrtf(v##it.x * v##it.x + v##it.y * v##it.y);
        E12(KMAG)

        // ---- stage W1 chunk (overlaps with k-loads above until barrier)
        __syncthreads();   // protect sW reuse across passes
        for (int t = tid; t < kNC * RPC; t += 256) {
            int j = t / RPC, i = t - j * RPC;
            sW[i][j] = w1[j * kIN + r0 + i];
        }
        __syncthreads();

#define PDECL(j) float a##j = 0.0f;
        E18(PDECL)

#define ROWF(it) { \
            const float* row = &sW[r32 + 32 * (it)][0]; \
            const float4 q0 = *reinterpret_cast<const float4*>(row); \
            const float4 q1 = *reinterpret_cast<const float4*>(row + 4); \
            const float4 q2 = *reinterpret_cast<const float4*>(row + 8); \
            const float4 q3 = *reinterpret_cast<const float4*>(row + 12); \
            const float2 q4 = *reinterpret_cast<const float2*>(row + 16); \
            const float f = f##it; \
            a0  = fmaf(f, q0.x, a0);  a1  = fmaf(f, q0.y, a1);  \
            a2  = fmaf(f, q0.z, a2);  a3  = fmaf(f, q0.w, a3);  \
            a4  = fmaf(f, q1.x, a4);  a5  = fmaf(f, q1.y, a5);  \
            a6  = fmaf(f, q1.z, a6);  a7  = fmaf(f, q1.w, a7);  \
            a8  = fmaf(f, q2.x, a8);  a9  = fmaf(f, q2.y, a9);  \
            a10 = fmaf(f, q2.z, a10); a11 = fmaf(f, q2.w, a11); \
            a12 = fmaf(f, q3.x, a12); a13 = fmaf(f, q3.y, a13); \
            a14 = fmaf(f, q3.z, a14); a15 = fmaf(f, q3.w, a15); \
            a16 = fmaf(f, q4.x, a16); a17 = fmaf(f, q4.y, a17); }
        E12(ROWF)

        // reduce lanes with stride 8 (same column) within the wave
#define WRED(j) { a##j += __shfl_down(a##j, 32, 64); a##j += __shfl_down(a##j, 16, 64); \
                  a##j += __shfl_down(a##j, 8, 64); }
        E18(WRED)
        if (lane < 8) {
#define SSTORE(j) sRed[wave][lane][j] = a##j;
            E18(SSTORE)
        }
        __syncthreads();
        if (tid < 8 * kNC) {
            int c = tid / kNC, j = tid - c * kNC;
            float s = sRed[0][c][j] + sRed[1][c][j] + sRed[2][c][j] + sRed[3][c][j];
            float* Pp = (pass == 0) ? Pa_part : Pq_part;
            Pp[((size_t)chunk * kB * kW + (size_t)b * kW + (w0 + c)) * kNC + j] = s;
        }
    }
}

// --------------------------------------------------------------------------
// K2: dense float4 reduce of the 8 chunk-partials.
// --------------------------------------------------------------------------
__global__ __launch_bounds__(256)
void reduce_kernel(const float4* __restrict__ Pa_part, const float4* __restrict__ Pq_part,
                   float4* __restrict__ Pa, float4* __restrict__ Pq) {
    const int n4 = kN / 4;
    int idx = blockIdx.x * 256 + threadIdx.x;
    if (idx >= 2 * n4) return;
    const float4* src = (idx < n4) ? Pa_part : Pq_part;
    float4* dst = (idx < n4) ? Pa : Pq;
    int n = (idx < n4) ? idx : idx - n4;
    float4 s = make_float4(0.f, 0.f, 0.f, 0.f);
#pragma unroll
    for (int c = 0; c < NCH; ++c) {
        float4 v = src[(size_t)c * n4 + n];
        s.x += v.x; s.y += v.y; s.z += v.z; s.w += v.w;
    }
    dst[n] = s;
}

// --------------------------------------------------------------------------
// K3: per acquiring column wi: heat = mean over wc in [left,right) of the
// 3-layer MLP + sigmoid. Scalar registers + asm fences (no spill).
// Wave-0 register mask; weights staged by waves 1-3 in parallel.
// --------------------------------------------------------------------------
__global__ __launch_bounds__(256)
void pair_kernel(const float* __restrict__ Pq, const float* __restrict__ Pa,
                 const float* __restrict__ am, const float* __restrict__ qmask,
                 const float* __restrict__ b1, const float* __restrict__ W2,
                 const float* __restrict__ b2, const float* __restrict__ W3,
                 const float* __restrict__ b3, const float* __restrict__ W4,
                 const float* __restrict__ b4, float* __restrict__ heat) {
    int wi = blockIdx.x, b = blockIdx.y, tid = threadIdx.x;
    if (!(qmask[b * kW + wi] > 0.0f)) return;
    int lane = tid & 63, wave = tid >> 6;

    __shared__ int sLR[2];
    __shared__ float2 sW2[kNC * kNC / 2], sW3[kNC * kNC / 2];   // row-major pairs
    __shared__ float sW4[kNC], sb1[kNC], sb2[kNC], sb3[kNC], sPq[kNC];
    __shared__ float sb4s, wred[4];

    mask_wave0(am, b, lane, wave, sLR);
    if (tid >= 64 && tid < 64 + kNC * kNC / 2) {          // waves 1-2
        int t = tid - 64;
        sW2[t] = reinterpret_cast<const float2*>(W2)[t];
        sW3[t] = reinterpret_cast<const float2*>(W3)[t];
    }
    if (tid >= 224 && tid < 224 + kNC) {                  // wave 3
        int j = tid - 224;
        sPq[j] = Pq[((size_t)(b * kW + wi)) * kNC + j];
        sW4[j] = W4[j]; sb1[j] = b1[j]; sb2[j] = b2[j]; sb3[j] = b3[j];
    }
    if (tid == 255) sb4s = b4[0];
    __syncthreads();

    int left  = ((sLR[0] == INT_MAX) ? 0 : sLR[0]) + 1;
    int right = kMID + ((sLR[1] == INT_MAX) ? 0 : sLR[1]);
    int span = right - left;

#define DOT2(S, k, v) (S[(k)*9+0].x*v##0  + S[(k)*9+0].y*v##1  + \
                       S[(k)*9+1].x*v##2  + S[(k)*9+1].y*v##3  + \
                       S[(k)*9+2].x*v##4  + S[(k)*9+2].y*v##5  + \
                       S[(k)*9+3].x*v##6  + S[(k)*9+3].y*v##7  + \
                       S[(k)*9+4].x*v##8  + S[(k)*9+4].y*v##9  + \
                       S[(k)*9+5].x*v##10 + S[(k)*9+5].y*v##11 + \
                       S[(k)*9+6].x*v##12 + S[(k)*9+6].y*v##13 + \
                       S[(k)*9+7].x*v##14 + S[(k)*9+7].y*v##15 + \
                       S[(k)*9+8].x*v##16 + S[(k)*9+8].y*v##17)

    float ssum = 0.0f;
    for (int wc = left + tid; wc < right; wc += 256) {
        const float* pa = Pa + (size_t)(b * kW + wc) * kNC;
#define L1(j) float x##j = fmaxf(sPq[j] + sb1[j] + pa[j], 0.0f);
        E18(L1)
        asm volatile("" ::: "memory");
#define L2(k) float y##k = fmaxf(sb2[k] + DOT2(sW2, k, x), 0.0f);
        E18(L2)
        asm volatile("" ::: "memory");
#define L3(k) float z##k = fmaxf(sb3[k] + DOT2(sW3, k, y), 0.0f);
        E18(L3)
        asm volatile("" ::: "memory");
        float t = sb4s +
            (sW4[0]*z0 + sW4[1]*z1 + sW4[2]*z2 + sW4[3]*z3 + sW4[4]*z4 + sW4[5]*z5 +
             sW4[6]*z6 + sW4[7]*z7 + sW4[8]*z8 + sW4[9]*z9 + sW4[10]*z10 + sW4[11]*z11 +
             sW4[12]*z12 + sW4[13]*z13 + sW4[14]*z14 + sW4[15]*z15 + sW4[16]*z16 + sW4[17]*z17);
        ssum += 1.0f / (1.0f + expf(-t));
    }

    ssum += __shfl_down(ssum, 32, 64); ssum += __shfl_down(ssum, 16, 64);
    ssum += __shfl_down(ssum,  8, 64); ssum += __shfl_down(ssum,  4, 64);
    ssum += __shfl_down(ssum,  2, 64); ssum += __shfl_down(ssum,  1, 64);
    if (lane == 0) wred[wave] = ssum;
    __syncthreads();
    if (tid == 0)
        heat[b * kW + wi] = (wred[0] + wred[1] + wred[2] + wred[3]) / (float)span;
}

// --------------------------------------------------------------------------
// K4: coalesced float4 broadcast: out[b,h,w] = qmask ? heat[b,w] : 0
// --------------------------------------------------------------------------
__global__ __launch_bounds__(256)
void out_kernel(const float* __restrict__ heat, const float* __restrict__ qm,
                float4* __restrict__ out) {
    const int n4 = kB * kH * kW / 4;
    int idx = blockIdx.x * 256 + threadIdx.x;
    if (idx >= n4) return;
    int w4 = idx % (kW / 4);
    int b = idx / (kH * kW / 4);
    int base = b * kW + 4 * w4;
    float4 v;
    v.x = (qm[base + 0] > 0.0f) ? heat[base + 0] : 0.0f;
    v.y = (qm[base + 1] > 0.0f) ? heat[base + 1] : 0.0f;
    v.z = (qm[base + 2] > 0.0f) ? heat[base + 2] : 0.0f;
    v.w = (qm[base + 3] > 0.0f) ? heat[base + 3] : 0.0f;
    out[idx] = v;
}

extern "C" void kernel_launch(void* const* d_in, const int* in_sizes, int n_in,
                              void* d_out, int out_size, void* d_ws, size_t ws_size,
                              hipStream_t stream) {
    const float* acquired       = (const float*)d_in[0];
    const float* acquiring      = (const float*)d_in[1];
    const float* acquired_mask  = (const float*)d_in[2];
    const float* acquiring_mask = (const float*)d_in[3];
    const float* W1 = (const float*)d_in[4];
    const float* b1 = (const float*)d_in[5];
    const float* W2 = (const float*)d_in[6];
    const float* b2 = (const float*)d_in[7];
    const float* W3 = (const float*)d_in[8];
    const float* b3 = (const float*)d_in[9];
    const float* W4 = (const float*)d_in[10];
    const float* b4 = (const float*)d_in[11];
    float* out = (float*)d_out;

    float* Pa_part = (float*)d_ws;                 // NCH * kN
    float* Pq_part = Pa_part + (size_t)NCH * kN;   // NCH * kN
    float* Pa      = Pq_part + (size_t)NCH * kN;   // kN
    float* Pq      = Pa + kN;                      // kN
    float* heat    = Pq + kN;                      // kB*kW

    proj_kernel<<<dim3(NGRP, NCH, kB), 256, 0, stream>>>(
        acquired, acquiring, acquired_mask, acquiring_mask, W1, Pq_part, Pa_part);
    reduce_kernel<<<(2 * (kN / 4) + 255) / 256, 256, 0, stream>>>(
        (const float4*)Pa_part, (const float4*)Pq_part, (float4*)Pa, (float4*)Pq);
    pair_kernel<<<dim3(kW, kB), 256, 0, stream>>>(
        Pq, Pa, acquired_mask, acquiring_mask,
        b1, W2, b2, W3, b3, W4, b4, heat);
    out_kernel<<<(kB * kH * kW / 4 + 255) / 256, 256, 0, stream>>>(
        heat, acquiring_mask, (float4*)out);
}